// Round 3
// baseline (651.247 us; speedup 1.0000x reference)
//
#include <hip/hip_runtime.h>

// ---------------------------------------------------------------------------
// NGNN GCNConv: out = relu((norm_dst * segsum_dst((x*norm_src)[src])) @ W + b) @ fc_W^T + fc_b
// N=100000 nodes, E=1600000 edges, D=128 everywhere.
//
// Pipeline (all on `stream`):
//   0. zero deg_in/deg_out/cursor                (ws)
//   T. transpose fc_W -> fcwT (ws)               (tiny)
//   1. degree count (int atomics)
//   2. exclusive scan of deg_in -> csr_off       (3-kernel scan)
//   3. csr fill: csr_src sorted by dst           (int atomics on cursor)
//   4. aggregation: 1 wave per dst node, float2/lane, 4-way edge unroll
//   5. fused GEMM: 64-row tile, 2x8 reg blocking (c=8 -> VALU-bound,
//      LDS/VALU cyc ratio 6/c = 0.75), weights read from global (L1/L2),
//      no weight LDS tile -> DS pipe unloaded.
// ---------------------------------------------------------------------------

__global__ void zero_kernel(int* __restrict__ p, int n) {
  int i = blockIdx.x * blockDim.x + threadIdx.x;
  int stride = gridDim.x * blockDim.x;
  for (; i < n; i += stride) p[i] = 0;
}

// fcwT[k][j] = fcW[j][k], 128x128
__global__ void transpose128_kernel(const float* __restrict__ in, float* __restrict__ out) {
  int idx = blockIdx.x * 256 + threadIdx.x;  // 0..16383
  int k = idx >> 7, j = idx & 127;
  out[idx] = in[j * 128 + k];
}

__global__ void degree_kernel(const int* __restrict__ src, const int* __restrict__ dst,
                              int* __restrict__ deg_out, int* __restrict__ deg_in, int E) {
  int e = blockIdx.x * blockDim.x + threadIdx.x;
  if (e < E) {
    atomicAdd(&deg_out[src[e]], 1);
    atomicAdd(&deg_in[dst[e]], 1);
  }
}

// per-1024-chunk exclusive scan of deg_in -> csr_off (block-local), totals -> bsum
__global__ void scan1_kernel(const int* __restrict__ deg_in, int* __restrict__ csr_off,
                             int* __restrict__ bsum, int N) {
  __shared__ int s[256];
  int tid = threadIdx.x;
  int base = blockIdx.x * 1024 + tid * 4;
  int v0 = 0, v1 = 0, v2 = 0, v3 = 0;
  if (base + 0 < N) v0 = deg_in[base + 0];
  if (base + 1 < N) v1 = deg_in[base + 1];
  if (base + 2 < N) v2 = deg_in[base + 2];
  if (base + 3 < N) v3 = deg_in[base + 3];
  int tot = v0 + v1 + v2 + v3;
  s[tid] = tot;
  __syncthreads();
  for (int off = 1; off < 256; off <<= 1) {
    int add = (tid >= off) ? s[tid - off] : 0;
    __syncthreads();
    s[tid] += add;
    __syncthreads();
  }
  int excl = s[tid] - tot;  // exclusive prefix within block
  if (base + 0 < N) csr_off[base + 0] = excl;
  if (base + 1 < N) csr_off[base + 1] = excl + v0;
  if (base + 2 < N) csr_off[base + 2] = excl + v0 + v1;
  if (base + 3 < N) csr_off[base + 3] = excl + v0 + v1 + v2;
  if (tid == 0) bsum[blockIdx.x] = s[255];
}

// single block: exclusive scan of block sums (nb <= 128)
__global__ void scan2_kernel(int* __restrict__ bsum, int nb) {
  __shared__ int s[128];
  int tid = threadIdx.x;
  int v = (tid < nb) ? bsum[tid] : 0;
  s[tid] = v;
  __syncthreads();
  for (int off = 1; off < 128; off <<= 1) {
    int add = (tid >= off) ? s[tid - off] : 0;
    __syncthreads();
    s[tid] += add;
    __syncthreads();
  }
  bsum[tid] = s[tid] - v;  // exclusive
}

// add block offsets; compute both norm vectors
__global__ void scan3_norm_kernel(int* __restrict__ csr_off, const int* __restrict__ bsum,
                                  const int* __restrict__ deg_out, const int* __restrict__ deg_in,
                                  float* __restrict__ norm_src, float* __restrict__ norm_dst,
                                  int N) {
  int i = blockIdx.x * blockDim.x + threadIdx.x;
  if (i < N) {
    csr_off[i] += bsum[i >> 10];
    int dgo = deg_out[i]; if (dgo < 1) dgo = 1;
    int dgi = deg_in[i];  if (dgi < 1) dgi = 1;
    norm_src[i] = 1.0f / sqrtf((float)dgo);
    norm_dst[i] = 1.0f / sqrtf((float)dgi);
  }
}

__global__ void fill_kernel(const int* __restrict__ src, const int* __restrict__ dst,
                            const int* __restrict__ csr_off, int* __restrict__ cursor,
                            int* __restrict__ csr_src, int E) {
  int e = blockIdx.x * blockDim.x + threadIdx.x;
  if (e < E) {
    int d = dst[e];
    int p = atomicAdd(&cursor[d], 1);
    csr_src[csr_off[d] + p] = src[e];
  }
}

// 1 wave per dst node; lane holds float2 of the 128-wide row.
// 4-way edge unroll: 4 independent index/norm/row loads in flight per wave.
__global__ __launch_bounds__(256) void agg_kernel(
    const float* __restrict__ x, const int* __restrict__ csr_src,
    const int* __restrict__ csr_off, const int* __restrict__ deg_in,
    const float* __restrict__ norm_src, const float* __restrict__ norm_dst,
    float* __restrict__ out, int N) {
  int wid = threadIdx.x >> 6;
  int lane = threadIdx.x & 63;
  int v = blockIdx.x * 4 + wid;
  if (v >= N) return;
  int start = csr_off[v];
  int cnt = deg_in[v];
  int end = start + cnt;
  const float2* __restrict__ x2 = (const float2*)x;

  float2 a0, a1, a2, a3;
  a0.x = a0.y = a1.x = a1.y = a2.x = a2.y = a3.x = a3.y = 0.f;

  int e = start;
  for (; e + 4 <= end; e += 4) {
    int s0 = csr_src[e + 0];
    int s1 = csr_src[e + 1];
    int s2 = csr_src[e + 2];
    int s3 = csr_src[e + 3];
    float n0 = norm_src[s0];
    float n1 = norm_src[s1];
    float n2 = norm_src[s2];
    float n3 = norm_src[s3];
    float2 v0 = x2[(size_t)s0 * 64 + lane];
    float2 v1 = x2[(size_t)s1 * 64 + lane];
    float2 v2 = x2[(size_t)s2 * 64 + lane];
    float2 v3 = x2[(size_t)s3 * 64 + lane];
    a0.x += v0.x * n0; a0.y += v0.y * n0;
    a1.x += v1.x * n1; a1.y += v1.y * n1;
    a2.x += v2.x * n2; a2.y += v2.y * n2;
    a3.x += v3.x * n3; a3.y += v3.y * n3;
  }
  for (; e < end; ++e) {
    int s = csr_src[e];
    float n = norm_src[s];
    float2 xv = x2[(size_t)s * 64 + lane];
    a0.x += xv.x * n; a0.y += xv.y * n;
  }

  float nd = norm_dst[v];
  float2 r;
  r.x = ((a0.x + a1.x) + (a2.x + a3.x)) * nd;
  r.y = ((a0.y + a1.y) + (a2.y + a3.y)) * nd;
  ((float2*)out)[(size_t)v * 64 + lane] = r;
}

// Fused double-GEMM, in-place on io.
// 64-row tile, 512 threads, 2 rows x 8 cols per thread. Weights from global.
// LDS: aggT 32KB + hT 32KB = 64KB -> 2 blocks/CU, 16 waves/CU.
__global__ __launch_bounds__(512) void gemm_fused_kernel(
    float* __restrict__ io, const float* __restrict__ W, const float* __restrict__ b,
    const float* __restrict__ fcwT, const float* __restrict__ fcb, int N) {
  __shared__ float aggT[64][128];
  __shared__ float hT[64][128];

  int t = threadIdx.x;
  int row0 = blockIdx.x * 64;
  size_t base = (size_t)row0 * 128;

  // stage 64x128 agg tile (coalesced float4)
  const float4* __restrict__ io4 = (const float4*)(io + base);
#pragma unroll
  for (int r = 0; r < 4; ++r) {
    int idx = r * 512 + t;       // float4 index in tile, 0..2047
    int rr = idx >> 5;           // row (32 float4 per row)
    float4 v = make_float4(0.f, 0.f, 0.f, 0.f);
    if (row0 + rr < N) v = io4[idx];
    *(float4*)&aggT[rr][(idx & 31) * 4] = v;
  }
  __syncthreads();

  int tj = t & 15;   // 16 col groups, j0 = 8*tj
  int ti = t >> 4;   // 32 row groups, i0 = 2*ti
  int j0 = 8 * tj, i0 = 2 * ti;

  // ---- phase 1: hT = relu(aggT @ W + b)
  {
    float acc[2][8];
    float4 b0 = *(const float4*)&b[j0];
    float4 b1 = *(const float4*)&b[j0 + 4];
#pragma unroll
    for (int q = 0; q < 2; ++q) {
      acc[q][0] = b0.x; acc[q][1] = b0.y; acc[q][2] = b0.z; acc[q][3] = b0.w;
      acc[q][4] = b1.x; acc[q][5] = b1.y; acc[q][6] = b1.z; acc[q][7] = b1.w;
    }
    for (int k = 0; k < 128; k += 4) {
      float4 a0 = *(const float4*)&aggT[i0 + 0][k];
      float4 a1 = *(const float4*)&aggT[i0 + 1][k];
#pragma unroll
      for (int kk = 0; kk < 4; ++kk) {
        float4 w0 = *(const float4*)&W[(size_t)(k + kk) * 128 + j0];
        float4 w1 = *(const float4*)&W[(size_t)(k + kk) * 128 + j0 + 4];
        float av0 = (kk == 0) ? a0.x : (kk == 1) ? a0.y : (kk == 2) ? a0.z : a0.w;
        float av1 = (kk == 0) ? a1.x : (kk == 1) ? a1.y : (kk == 2) ? a1.z : a1.w;
        acc[0][0] += av0 * w0.x; acc[0][1] += av0 * w0.y;
        acc[0][2] += av0 * w0.z; acc[0][3] += av0 * w0.w;
        acc[0][4] += av0 * w1.x; acc[0][5] += av0 * w1.y;
        acc[0][6] += av0 * w1.z; acc[0][7] += av0 * w1.w;
        acc[1][0] += av1 * w0.x; acc[1][1] += av1 * w0.y;
        acc[1][2] += av1 * w0.z; acc[1][3] += av1 * w0.w;
        acc[1][4] += av1 * w1.x; acc[1][5] += av1 * w1.y;
        acc[1][6] += av1 * w1.z; acc[1][7] += av1 * w1.w;
      }
    }
#pragma unroll
    for (int q = 0; q < 2; ++q) {
      float4 h0, h1;
      h0.x = fmaxf(acc[q][0], 0.f); h0.y = fmaxf(acc[q][1], 0.f);
      h0.z = fmaxf(acc[q][2], 0.f); h0.w = fmaxf(acc[q][3], 0.f);
      h1.x = fmaxf(acc[q][4], 0.f); h1.y = fmaxf(acc[q][5], 0.f);
      h1.z = fmaxf(acc[q][6], 0.f); h1.w = fmaxf(acc[q][7], 0.f);
      *(float4*)&hT[i0 + q][j0] = h0;
      *(float4*)&hT[i0 + q][j0 + 4] = h1;
    }
  }
  __syncthreads();

  // ---- phase 2: out = hT @ fcwT + fcb (fcwT[k][j] pre-transposed)
  {
    float acc[2][8];
    float4 b0 = *(const float4*)&fcb[j0];
    float4 b1 = *(const float4*)&fcb[j0 + 4];
#pragma unroll
    for (int q = 0; q < 2; ++q) {
      acc[q][0] = b0.x; acc[q][1] = b0.y; acc[q][2] = b0.z; acc[q][3] = b0.w;
      acc[q][4] = b1.x; acc[q][5] = b1.y; acc[q][6] = b1.z; acc[q][7] = b1.w;
    }
    for (int k = 0; k < 128; k += 4) {
      float4 a0 = *(const float4*)&hT[i0 + 0][k];
      float4 a1 = *(const float4*)&hT[i0 + 1][k];
#pragma unroll
      for (int kk = 0; kk < 4; ++kk) {
        float4 w0 = *(const float4*)&fcwT[(size_t)(k + kk) * 128 + j0];
        float4 w1 = *(const float4*)&fcwT[(size_t)(k + kk) * 128 + j0 + 4];
        float av0 = (kk == 0) ? a0.x : (kk == 1) ? a0.y : (kk == 2) ? a0.z : a0.w;
        float av1 = (kk == 0) ? a1.x : (kk == 1) ? a1.y : (kk == 2) ? a1.z : a1.w;
        acc[0][0] += av0 * w0.x; acc[0][1] += av0 * w0.y;
        acc[0][2] += av0 * w0.z; acc[0][3] += av0 * w0.w;
        acc[0][4] += av0 * w1.x; acc[0][5] += av0 * w1.y;
        acc[0][6] += av0 * w1.z; acc[0][7] += av0 * w1.w;
        acc[1][0] += av1 * w0.x; acc[1][1] += av1 * w0.y;
        acc[1][2] += av1 * w0.z; acc[1][3] += av1 * w0.w;
        acc[1][4] += av1 * w1.x; acc[1][5] += av1 * w1.y;
        acc[1][6] += av1 * w1.z; acc[1][7] += av1 * w1.w;
      }
    }
#pragma unroll
    for (int q = 0; q < 2; ++q) {
      int rr = i0 + q;
      if (row0 + rr < N) {
        float4 o0, o1;
        o0.x = acc[q][0]; o0.y = acc[q][1]; o0.z = acc[q][2]; o0.w = acc[q][3];
        o1.x = acc[q][4]; o1.y = acc[q][5]; o1.z = acc[q][6]; o1.w = acc[q][7];
        *(float4*)&io[base + (size_t)rr * 128 + j0] = o0;
        *(float4*)&io[base + (size_t)rr * 128 + j0 + 4] = o1;
      }
    }
  }
}

extern "C" void kernel_launch(void* const* d_in, const int* in_sizes, int n_in,
                              void* d_out, int out_size, void* d_ws, size_t ws_size,
                              hipStream_t stream) {
  const float* x   = (const float*)d_in[0];
  const int* src   = (const int*)d_in[1];
  const int* dst   = (const int*)d_in[2];
  const float* W   = (const float*)d_in[3];
  const float* b   = (const float*)d_in[4];
  const float* fcW = (const float*)d_in[5];
  const float* fcb = (const float*)d_in[6];
  float* out = (float*)d_out;

  const int N = in_sizes[0] / 128;
  const int E = in_sizes[1];

  // ws layout (ints), NA = N rounded up to 1024
  const int NA = ((N + 1023) / 1024) * 1024;
  int* wsi = (int*)d_ws;
  int*   deg_in   = wsi + 0 * (size_t)NA;
  int*   deg_out  = wsi + 1 * (size_t)NA;
  int*   cursor   = wsi + 2 * (size_t)NA;
  float* norm_src = (float*)(wsi + 3 * (size_t)NA);
  float* norm_dst = (float*)(wsi + 4 * (size_t)NA);
  int*   csr_off  = wsi + 5 * (size_t)NA;
  int*   bsum     = wsi + 6 * (size_t)NA;          // 256 ints
  int*   csr_src  = wsi + 6 * (size_t)NA + 256;    // E ints
  float* fcwT     = (float*)(csr_src + E);         // 16384 floats

  const int NB1 = (N + 1023) / 1024;  // 98 blocks for N=100000 (must be <=128)

  // 0. zero deg_in, deg_out, cursor (contiguous 3*NA ints)
  zero_kernel<<<512, 256, 0, stream>>>(wsi, 3 * NA);
  // T. fcwT = fcW^T
  transpose128_kernel<<<64, 256, 0, stream>>>(fcW, fcwT);
  // 1. degrees
  degree_kernel<<<(E + 255) / 256, 256, 0, stream>>>(src, dst, deg_out, deg_in, E);
  // 2. scan deg_in -> csr_off
  scan1_kernel<<<NB1, 256, 0, stream>>>(deg_in, csr_off, bsum, N);
  scan2_kernel<<<1, 128, 0, stream>>>(bsum, NB1);
  scan3_norm_kernel<<<(N + 255) / 256, 256, 0, stream>>>(csr_off, bsum, deg_out, deg_in,
                                                         norm_src, norm_dst, N);
  // 3. fill CSR (src indices grouped by dst)
  fill_kernel<<<(E + 255) / 256, 256, 0, stream>>>(src, dst, csr_off, cursor, csr_src, E);
  // 4. aggregate: one wave per node -> d_out holds normalized agg
  agg_kernel<<<(N + 3) / 4, 256, 0, stream>>>(x, csr_src, csr_off, deg_in,
                                              norm_src, norm_dst, out, N);
  // 5. fused GEMMs in-place on d_out (64-row tiles)
  gemm_fused_kernel<<<(N + 63) / 64, 512, 0, stream>>>(out, W, b, fcwT, fcb, N);
}

// Round 4
// 564.559 us; speedup vs baseline: 1.1536x; 1.1536x over previous
//
#include <hip/hip_runtime.h>

// ---------------------------------------------------------------------------
// NGNN GCNConv: out = relu((norm_dst * segsum_dst((x*norm_src)[src])) @ W + b) @ fc_W^T + fc_b
// N=100000 nodes, E=1600000 edges, D=128 everywhere.
//
// GEMM strategy (R3): weights are wave-uniform -> read via SCALAR loads
// (s_load, separate pipe + SGPR broadcast into v_fma). A-operand from LDS
// (row-major, pad to 132 floats -> 2-way bank aliasing = free). Lane = row,
// wave owns 16 columns. VALU-bound by construction:
//   per block: VALU 16.4k cyc/SIMD vs DS ~7.5k cyc/CU.
// ---------------------------------------------------------------------------

__global__ void zero_kernel(int* __restrict__ p, int n) {
  int i = blockIdx.x * blockDim.x + threadIdx.x;
  int stride = gridDim.x * blockDim.x;
  for (; i < n; i += stride) p[i] = 0;
}

// fcwT[k][j] = fcW[j][k], 128x128
__global__ void transpose128_kernel(const float* __restrict__ in, float* __restrict__ out) {
  int idx = blockIdx.x * 256 + threadIdx.x;  // 0..16383
  int k = idx >> 7, j = idx & 127;
  out[idx] = in[j * 128 + k];
}

__global__ void degree_kernel(const int* __restrict__ src, const int* __restrict__ dst,
                              int* __restrict__ deg_out, int* __restrict__ deg_in, int E) {
  int e = blockIdx.x * blockDim.x + threadIdx.x;
  if (e < E) {
    atomicAdd(&deg_out[src[e]], 1);
    atomicAdd(&deg_in[dst[e]], 1);
  }
}

// per-1024-chunk exclusive scan of deg_in -> csr_off (block-local), totals -> bsum
__global__ void scan1_kernel(const int* __restrict__ deg_in, int* __restrict__ csr_off,
                             int* __restrict__ bsum, int N) {
  __shared__ int s[256];
  int tid = threadIdx.x;
  int base = blockIdx.x * 1024 + tid * 4;
  int v0 = 0, v1 = 0, v2 = 0, v3 = 0;
  if (base + 0 < N) v0 = deg_in[base + 0];
  if (base + 1 < N) v1 = deg_in[base + 1];
  if (base + 2 < N) v2 = deg_in[base + 2];
  if (base + 3 < N) v3 = deg_in[base + 3];
  int tot = v0 + v1 + v2 + v3;
  s[tid] = tot;
  __syncthreads();
  for (int off = 1; off < 256; off <<= 1) {
    int add = (tid >= off) ? s[tid - off] : 0;
    __syncthreads();
    s[tid] += add;
    __syncthreads();
  }
  int excl = s[tid] - tot;  // exclusive prefix within block
  if (base + 0 < N) csr_off[base + 0] = excl;
  if (base + 1 < N) csr_off[base + 1] = excl + v0;
  if (base + 2 < N) csr_off[base + 2] = excl + v0 + v1;
  if (base + 3 < N) csr_off[base + 3] = excl + v0 + v1 + v2;
  if (tid == 0) bsum[blockIdx.x] = s[255];
}

// single block: exclusive scan of block sums (nb <= 128)
__global__ void scan2_kernel(int* __restrict__ bsum, int nb) {
  __shared__ int s[128];
  int tid = threadIdx.x;
  int v = (tid < nb) ? bsum[tid] : 0;
  s[tid] = v;
  __syncthreads();
  for (int off = 1; off < 128; off <<= 1) {
    int add = (tid >= off) ? s[tid - off] : 0;
    __syncthreads();
    s[tid] += add;
    __syncthreads();
  }
  bsum[tid] = s[tid] - v;  // exclusive
}

// add block offsets; compute both norm vectors
__global__ void scan3_norm_kernel(int* __restrict__ csr_off, const int* __restrict__ bsum,
                                  const int* __restrict__ deg_out, const int* __restrict__ deg_in,
                                  float* __restrict__ norm_src, float* __restrict__ norm_dst,
                                  int N) {
  int i = blockIdx.x * blockDim.x + threadIdx.x;
  if (i < N) {
    csr_off[i] += bsum[i >> 10];
    int dgo = deg_out[i]; if (dgo < 1) dgo = 1;
    int dgi = deg_in[i];  if (dgi < 1) dgi = 1;
    norm_src[i] = 1.0f / sqrtf((float)dgo);
    norm_dst[i] = 1.0f / sqrtf((float)dgi);
  }
}

__global__ void fill_kernel(const int* __restrict__ src, const int* __restrict__ dst,
                            const int* __restrict__ csr_off, int* __restrict__ cursor,
                            int* __restrict__ csr_src, int E) {
  int e = blockIdx.x * blockDim.x + threadIdx.x;
  if (e < E) {
    int d = dst[e];
    int p = atomicAdd(&cursor[d], 1);
    csr_src[csr_off[d] + p] = src[e];
  }
}

// 1 wave per dst node; lane holds float2 of the 128-wide row.
// 4-way edge unroll: 4 independent index/norm/row loads in flight per wave.
__global__ __launch_bounds__(256) void agg_kernel(
    const float* __restrict__ x, const int* __restrict__ csr_src,
    const int* __restrict__ csr_off, const int* __restrict__ deg_in,
    const float* __restrict__ norm_src, const float* __restrict__ norm_dst,
    float* __restrict__ out, int N) {
  int wid = threadIdx.x >> 6;
  int lane = threadIdx.x & 63;
  int v = blockIdx.x * 4 + wid;
  if (v >= N) return;
  int start = csr_off[v];
  int cnt = deg_in[v];
  int end = start + cnt;
  const float2* __restrict__ x2 = (const float2*)x;

  float2 a0, a1, a2, a3;
  a0.x = a0.y = a1.x = a1.y = a2.x = a2.y = a3.x = a3.y = 0.f;

  int e = start;
  for (; e + 4 <= end; e += 4) {
    int s0 = csr_src[e + 0];
    int s1 = csr_src[e + 1];
    int s2 = csr_src[e + 2];
    int s3 = csr_src[e + 3];
    float n0 = norm_src[s0];
    float n1 = norm_src[s1];
    float n2 = norm_src[s2];
    float n3 = norm_src[s3];
    float2 v0 = x2[(size_t)s0 * 64 + lane];
    float2 v1 = x2[(size_t)s1 * 64 + lane];
    float2 v2 = x2[(size_t)s2 * 64 + lane];
    float2 v3 = x2[(size_t)s3 * 64 + lane];
    a0.x += v0.x * n0; a0.y += v0.y * n0;
    a1.x += v1.x * n1; a1.y += v1.y * n1;
    a2.x += v2.x * n2; a2.y += v2.y * n2;
    a3.x += v3.x * n3; a3.y += v3.y * n3;
  }
  for (; e < end; ++e) {
    int s = csr_src[e];
    float n = norm_src[s];
    float2 xv = x2[(size_t)s * 64 + lane];
    a0.x += xv.x * n; a0.y += xv.y * n;
  }

  float nd = norm_dst[v];
  float2 r;
  r.x = ((a0.x + a1.x) + (a2.x + a3.x)) * nd;
  r.y = ((a0.y + a1.y) + (a2.y + a3.y)) * nd;
  ((float2*)out)[(size_t)v * 64 + lane] = r;
}

// Fused double-GEMM, in-place on io. 64-row tile, 512 threads (8 waves).
// lane = row (0..63); wave w owns columns [16w, 16w+16).
// Weights via wave-uniform scalar loads (SMEM pipe + SGPR-broadcast FMA).
// LDS: aggT + hT, row stride 132 floats (528B): within a 16-lane phase group,
// banks (4*lane + 4*c) % 32 give 2 lanes per 4-bank window -> free.
__global__ __launch_bounds__(512) void gemm_fused_kernel(
    float* __restrict__ io, const float* __restrict__ W, const float* __restrict__ b,
    const float* __restrict__ fcwT, const float* __restrict__ fcb, int N) {
  __shared__ float aggT[64][132];
  __shared__ float hT[64][132];

  int t = threadIdx.x;
  int lane = t & 63;
  int wave = __builtin_amdgcn_readfirstlane(t >> 6);  // force wave-uniform
  int j0 = wave * 16;
  int row0 = blockIdx.x * 64;
  size_t base = (size_t)row0 * 128;

  // stage 64x128 agg tile (coalesced float4)
  const float4* __restrict__ io4 = (const float4*)(io + base);
#pragma unroll
  for (int r = 0; r < 4; ++r) {
    int idx = r * 512 + t;       // float4 index in tile, 0..2047
    int rr = idx >> 5;           // row (32 float4 per row)
    float4 v = make_float4(0.f, 0.f, 0.f, 0.f);
    if (row0 + rr < N) v = io4[idx];
    *(float4*)&aggT[rr][(idx & 31) * 4] = v;
  }
  __syncthreads();

  // ---- phase 1: hT[lane][j0..j0+15] = relu(aggT[lane][:] @ W[:, j0..j0+15] + b)
  {
    float acc[16];
#pragma unroll
    for (int q = 0; q < 4; ++q) {
      float4 b4 = *(const float4*)&b[j0 + 4 * q];   // uniform -> s_load
      acc[4 * q + 0] = b4.x; acc[4 * q + 1] = b4.y;
      acc[4 * q + 2] = b4.z; acc[4 * q + 3] = b4.w;
    }
#pragma unroll 4
    for (int k4 = 0; k4 < 32; ++k4) {
      float4 a4 = *(const float4*)&aggT[lane][k4 * 4];
#pragma unroll
      for (int kk = 0; kk < 4; ++kk) {
        float av = (kk == 0) ? a4.x : (kk == 1) ? a4.y : (kk == 2) ? a4.z : a4.w;
        const float* Wrow = &W[(size_t)(k4 * 4 + kk) * 128 + j0];  // uniform
#pragma unroll
        for (int q = 0; q < 4; ++q) {
          float4 w4 = *(const float4*)&Wrow[4 * q];  // s_load_dwordx4
          acc[4 * q + 0] += av * w4.x;
          acc[4 * q + 1] += av * w4.y;
          acc[4 * q + 2] += av * w4.z;
          acc[4 * q + 3] += av * w4.w;
        }
      }
    }
#pragma unroll
    for (int q = 0; q < 4; ++q) {
      float4 h4;
      h4.x = fmaxf(acc[4 * q + 0], 0.f);
      h4.y = fmaxf(acc[4 * q + 1], 0.f);
      h4.z = fmaxf(acc[4 * q + 2], 0.f);
      h4.w = fmaxf(acc[4 * q + 3], 0.f);
      *(float4*)&hT[lane][j0 + 4 * q] = h4;
    }
  }
  __syncthreads();

  // ---- phase 2: out[lane][j0..j0+15] = hT[lane][:] @ fcwT[:, j0..j0+15] + fcb
  {
    float acc[16];
#pragma unroll
    for (int q = 0; q < 4; ++q) {
      float4 b4 = *(const float4*)&fcb[j0 + 4 * q];
      acc[4 * q + 0] = b4.x; acc[4 * q + 1] = b4.y;
      acc[4 * q + 2] = b4.z; acc[4 * q + 3] = b4.w;
    }
#pragma unroll 4
    for (int k4 = 0; k4 < 32; ++k4) {
      float4 a4 = *(const float4*)&hT[lane][k4 * 4];
#pragma unroll
      for (int kk = 0; kk < 4; ++kk) {
        float av = (kk == 0) ? a4.x : (kk == 1) ? a4.y : (kk == 2) ? a4.z : a4.w;
        const float* Wrow = &fcwT[(size_t)(k4 * 4 + kk) * 128 + j0];
#pragma unroll
        for (int q = 0; q < 4; ++q) {
          float4 w4 = *(const float4*)&Wrow[4 * q];
          acc[4 * q + 0] += av * w4.x;
          acc[4 * q + 1] += av * w4.y;
          acc[4 * q + 2] += av * w4.z;
          acc[4 * q + 3] += av * w4.w;
        }
      }
    }
    // stage result into aggT (free after phase 1) for coalesced store
#pragma unroll
    for (int q = 0; q < 4; ++q) {
      float4 o4;
      o4.x = acc[4 * q + 0]; o4.y = acc[4 * q + 1];
      o4.z = acc[4 * q + 2]; o4.w = acc[4 * q + 3];
      *(float4*)&aggT[lane][j0 + 4 * q] = o4;
    }
  }
  __syncthreads();

  // coalesced copy-out
  float4* __restrict__ o4p = (float4*)(io + base);
#pragma unroll
  for (int r = 0; r < 4; ++r) {
    int idx = r * 512 + t;
    int rr = idx >> 5;
    if (row0 + rr < N) o4p[idx] = *(const float4*)&aggT[rr][(idx & 31) * 4];
  }
}

extern "C" void kernel_launch(void* const* d_in, const int* in_sizes, int n_in,
                              void* d_out, int out_size, void* d_ws, size_t ws_size,
                              hipStream_t stream) {
  const float* x   = (const float*)d_in[0];
  const int* src   = (const int*)d_in[1];
  const int* dst   = (const int*)d_in[2];
  const float* W   = (const float*)d_in[3];
  const float* b   = (const float*)d_in[4];
  const float* fcW = (const float*)d_in[5];
  const float* fcb = (const float*)d_in[6];
  float* out = (float*)d_out;

  const int N = in_sizes[0] / 128;
  const int E = in_sizes[1];

  // ws layout (ints), NA = N rounded up to 1024
  const int NA = ((N + 1023) / 1024) * 1024;
  int* wsi = (int*)d_ws;
  int*   deg_in   = wsi + 0 * (size_t)NA;
  int*   deg_out  = wsi + 1 * (size_t)NA;
  int*   cursor   = wsi + 2 * (size_t)NA;
  float* norm_src = (float*)(wsi + 3 * (size_t)NA);
  float* norm_dst = (float*)(wsi + 4 * (size_t)NA);
  int*   csr_off  = wsi + 5 * (size_t)NA;
  int*   bsum     = wsi + 6 * (size_t)NA;          // 256 ints
  int*   csr_src  = wsi + 6 * (size_t)NA + 256;    // E ints
  float* fcwT     = (float*)(csr_src + E);         // 16384 floats

  const int NB1 = (N + 1023) / 1024;  // 98 blocks for N=100000 (must be <=128)

  // 0. zero deg_in, deg_out, cursor (contiguous 3*NA ints)
  zero_kernel<<<512, 256, 0, stream>>>(wsi, 3 * NA);
  // T. fcwT = fcW^T
  transpose128_kernel<<<64, 256, 0, stream>>>(fcW, fcwT);
  // 1. degrees
  degree_kernel<<<(E + 255) / 256, 256, 0, stream>>>(src, dst, deg_out, deg_in, E);
  // 2. scan deg_in -> csr_off
  scan1_kernel<<<NB1, 256, 0, stream>>>(deg_in, csr_off, bsum, N);
  scan2_kernel<<<1, 128, 0, stream>>>(bsum, NB1);
  scan3_norm_kernel<<<(N + 255) / 256, 256, 0, stream>>>(csr_off, bsum, deg_out, deg_in,
                                                         norm_src, norm_dst, N);
  // 3. fill CSR (src indices grouped by dst)
  fill_kernel<<<(E + 255) / 256, 256, 0, stream>>>(src, dst, csr_off, cursor, csr_src, E);
  // 4. aggregate: one wave per node -> d_out holds normalized agg
  agg_kernel<<<(N + 3) / 4, 256, 0, stream>>>(x, csr_src, csr_off, deg_in,
                                              norm_src, norm_dst, out, N);
  // 5. fused GEMMs in-place on d_out (64-row tiles)
  gemm_fused_kernel<<<(N + 63) / 64, 512, 0, stream>>>(out, W, b, fcwT, fcb, N);
}

// Round 5
// 490.899 us; speedup vs baseline: 1.3266x; 1.1500x over previous
//
#include <hip/hip_runtime.h>

// ---------------------------------------------------------------------------
// NGNN GCNConv: out = relu((norm_dst * segsum_dst((x*norm_src)[src])) @ W + b) @ fc_W^T + fc_b
// N=100000 nodes, E=1600000 edges, D=128 everywhere.
//
// R4 pipeline (atomic-count-minimized; 4.8M -> 3.2M global atomics):
//   0. zero cursor/deg_out (2NA ints)
//   T. transpose fc_W -> fcwT
//   1. fill_deg: per edge: deg_out[s]++; p=cursor[d]++; bucket[d*64+p]=s
//      (cursor doubles as deg_in; fixed CAP=64 buckets kill the CSR scan:
//       Poisson(16) tail P(deg>=64) ~ 2e-18)
//   2. norm: norm_src=rsqrt(max(deg_out,1)), norm_dst=rsqrt(max(cursor,1))
//   3. agg: 1 wave per dst node, float2/lane, 4-way unroll, bucket reads
//   4. gemm_fused: scalar-pipe weights (s_load broadcast), LDS A-operand,
//      lane=row, wave=16 cols. (R3 win: VMEM/DS pipes unloaded.)
// ---------------------------------------------------------------------------

__global__ void zero_kernel(int* __restrict__ p, int n) {
  int i = blockIdx.x * blockDim.x + threadIdx.x;
  int stride = gridDim.x * blockDim.x;
  for (; i < n; i += stride) p[i] = 0;
}

// fcwT[k][j] = fcW[j][k], 128x128
__global__ void transpose128_kernel(const float* __restrict__ in, float* __restrict__ out) {
  int idx = blockIdx.x * 256 + threadIdx.x;  // 0..16383
  int k = idx >> 7, j = idx & 127;
  out[idx] = in[j * 128 + k];
}

// One pass over edges: count deg_out, and bucket-scatter src by dst.
// 4 edges per thread via int4 loads.
__global__ void fill_deg_kernel(const int* __restrict__ src, const int* __restrict__ dst,
                                int* __restrict__ deg_out, int* __restrict__ cursor,
                                int* __restrict__ bucket, int E) {
  int i = blockIdx.x * blockDim.x + threadIdx.x;
  int e0 = i * 4;
  if (e0 + 3 < E) {
    int4 s4 = *(const int4*)&src[e0];
    int4 d4 = *(const int4*)&dst[e0];
    atomicAdd(&deg_out[s4.x], 1);
    atomicAdd(&deg_out[s4.y], 1);
    atomicAdd(&deg_out[s4.z], 1);
    atomicAdd(&deg_out[s4.w], 1);
    int p0 = atomicAdd(&cursor[d4.x], 1);
    int p1 = atomicAdd(&cursor[d4.y], 1);
    int p2 = atomicAdd(&cursor[d4.z], 1);
    int p3 = atomicAdd(&cursor[d4.w], 1);
    bucket[(d4.x << 6) + p0] = s4.x;
    bucket[(d4.y << 6) + p1] = s4.y;
    bucket[(d4.z << 6) + p2] = s4.z;
    bucket[(d4.w << 6) + p3] = s4.w;
  } else {
    for (int e = e0; e < E; ++e) {
      int s = src[e], d = dst[e];
      atomicAdd(&deg_out[s], 1);
      int p = atomicAdd(&cursor[d], 1);
      bucket[(d << 6) + p] = s;
    }
  }
}

__global__ void norm_kernel(const int* __restrict__ deg_out, const int* __restrict__ cursor,
                            float* __restrict__ norm_src, float* __restrict__ norm_dst, int N) {
  int i = blockIdx.x * blockDim.x + threadIdx.x;
  if (i < N) {
    int dgo = deg_out[i]; if (dgo < 1) dgo = 1;
    int dgi = cursor[i];  if (dgi < 1) dgi = 1;
    norm_src[i] = 1.0f / sqrtf((float)dgo);
    norm_dst[i] = 1.0f / sqrtf((float)dgi);
  }
}

// 1 wave per dst node; lane holds float2 of the 128-wide row.
// 4-way edge unroll: 4 independent index/norm/row loads in flight per wave.
__global__ __launch_bounds__(256) void agg_kernel(
    const float* __restrict__ x, const int* __restrict__ bucket,
    const int* __restrict__ cursor,
    const float* __restrict__ norm_src, const float* __restrict__ norm_dst,
    float* __restrict__ out, int N) {
  int wid = threadIdx.x >> 6;
  int lane = threadIdx.x & 63;
  int v = blockIdx.x * 4 + wid;
  if (v >= N) return;
  int start = v << 6;
  int cnt = cursor[v];
  int end = start + cnt;
  const float2* __restrict__ x2 = (const float2*)x;

  float2 a0, a1, a2, a3;
  a0.x = a0.y = a1.x = a1.y = a2.x = a2.y = a3.x = a3.y = 0.f;

  int e = start;
  for (; e + 4 <= end; e += 4) {
    int s0 = bucket[e + 0];
    int s1 = bucket[e + 1];
    int s2 = bucket[e + 2];
    int s3 = bucket[e + 3];
    float n0 = norm_src[s0];
    float n1 = norm_src[s1];
    float n2 = norm_src[s2];
    float n3 = norm_src[s3];
    float2 v0 = x2[(size_t)s0 * 64 + lane];
    float2 v1 = x2[(size_t)s1 * 64 + lane];
    float2 v2 = x2[(size_t)s2 * 64 + lane];
    float2 v3 = x2[(size_t)s3 * 64 + lane];
    a0.x += v0.x * n0; a0.y += v0.y * n0;
    a1.x += v1.x * n1; a1.y += v1.y * n1;
    a2.x += v2.x * n2; a2.y += v2.y * n2;
    a3.x += v3.x * n3; a3.y += v3.y * n3;
  }
  for (; e < end; ++e) {
    int s = bucket[e];
    float n = norm_src[s];
    float2 xv = x2[(size_t)s * 64 + lane];
    a0.x += xv.x * n; a0.y += xv.y * n;
  }

  float nd = norm_dst[v];
  float2 r;
  r.x = ((a0.x + a1.x) + (a2.x + a3.x)) * nd;
  r.y = ((a0.y + a1.y) + (a2.y + a3.y)) * nd;
  ((float2*)out)[(size_t)v * 64 + lane] = r;
}

// Fused double-GEMM, in-place on io. 64-row tile, 512 threads (8 waves).
// lane = row (0..63); wave w owns columns [16w, 16w+16).
// Weights via wave-uniform scalar loads (SMEM pipe + SGPR-broadcast FMA).
__global__ __launch_bounds__(512) void gemm_fused_kernel(
    float* __restrict__ io, const float* __restrict__ W, const float* __restrict__ b,
    const float* __restrict__ fcwT, const float* __restrict__ fcb, int N) {
  __shared__ float aggT[64][132];
  __shared__ float hT[64][132];

  int t = threadIdx.x;
  int lane = t & 63;
  int wave = __builtin_amdgcn_readfirstlane(t >> 6);  // force wave-uniform
  int j0 = wave * 16;
  int row0 = blockIdx.x * 64;
  size_t base = (size_t)row0 * 128;

  // stage 64x128 agg tile (coalesced float4)
  const float4* __restrict__ io4 = (const float4*)(io + base);
#pragma unroll
  for (int r = 0; r < 4; ++r) {
    int idx = r * 512 + t;       // float4 index in tile, 0..2047
    int rr = idx >> 5;           // row (32 float4 per row)
    float4 v = make_float4(0.f, 0.f, 0.f, 0.f);
    if (row0 + rr < N) v = io4[idx];
    *(float4*)&aggT[rr][(idx & 31) * 4] = v;
  }
  __syncthreads();

  // ---- phase 1: hT[lane][j0..j0+15] = relu(aggT[lane][:] @ W[:, j0..j0+15] + b)
  {
    float acc[16];
#pragma unroll
    for (int q = 0; q < 4; ++q) {
      float4 b4 = *(const float4*)&b[j0 + 4 * q];   // uniform -> s_load
      acc[4 * q + 0] = b4.x; acc[4 * q + 1] = b4.y;
      acc[4 * q + 2] = b4.z; acc[4 * q + 3] = b4.w;
    }
#pragma unroll 4
    for (int k4 = 0; k4 < 32; ++k4) {
      float4 a4 = *(const float4*)&aggT[lane][k4 * 4];
#pragma unroll
      for (int kk = 0; kk < 4; ++kk) {
        float av = (kk == 0) ? a4.x : (kk == 1) ? a4.y : (kk == 2) ? a4.z : a4.w;
        const float* Wrow = &W[(size_t)(k4 * 4 + kk) * 128 + j0];  // uniform
#pragma unroll
        for (int q = 0; q < 4; ++q) {
          float4 w4 = *(const float4*)&Wrow[4 * q];  // s_load_dwordx4
          acc[4 * q + 0] += av * w4.x;
          acc[4 * q + 1] += av * w4.y;
          acc[4 * q + 2] += av * w4.z;
          acc[4 * q + 3] += av * w4.w;
        }
      }
    }
#pragma unroll
    for (int q = 0; q < 4; ++q) {
      float4 h4;
      h4.x = fmaxf(acc[4 * q + 0], 0.f);
      h4.y = fmaxf(acc[4 * q + 1], 0.f);
      h4.z = fmaxf(acc[4 * q + 2], 0.f);
      h4.w = fmaxf(acc[4 * q + 3], 0.f);
      *(float4*)&hT[lane][j0 + 4 * q] = h4;
    }
  }
  __syncthreads();

  // ---- phase 2: out[lane][j0..j0+15] = hT[lane][:] @ fcwT[:, j0..j0+15] + fcb
  {
    float acc[16];
#pragma unroll
    for (int q = 0; q < 4; ++q) {
      float4 b4 = *(const float4*)&fcb[j0 + 4 * q];
      acc[4 * q + 0] = b4.x; acc[4 * q + 1] = b4.y;
      acc[4 * q + 2] = b4.z; acc[4 * q + 3] = b4.w;
    }
#pragma unroll 4
    for (int k4 = 0; k4 < 32; ++k4) {
      float4 a4 = *(const float4*)&hT[lane][k4 * 4];
#pragma unroll
      for (int kk = 0; kk < 4; ++kk) {
        float av = (kk == 0) ? a4.x : (kk == 1) ? a4.y : (kk == 2) ? a4.z : a4.w;
        const float* Wrow = &fcwT[(size_t)(k4 * 4 + kk) * 128 + j0];
#pragma unroll
        for (int q = 0; q < 4; ++q) {
          float4 w4 = *(const float4*)&Wrow[4 * q];
          acc[4 * q + 0] += av * w4.x;
          acc[4 * q + 1] += av * w4.y;
          acc[4 * q + 2] += av * w4.z;
          acc[4 * q + 3] += av * w4.w;
        }
      }
    }
    // stage result into aggT (free after phase 1) for coalesced store
#pragma unroll
    for (int q = 0; q < 4; ++q) {
      float4 o4;
      o4.x = acc[4 * q + 0]; o4.y = acc[4 * q + 1];
      o4.z = acc[4 * q + 2]; o4.w = acc[4 * q + 3];
      *(float4*)&aggT[lane][j0 + 4 * q] = o4;
    }
  }
  __syncthreads();

  // coalesced copy-out
  float4* __restrict__ o4p = (float4*)(io + base);
#pragma unroll
  for (int r = 0; r < 4; ++r) {
    int idx = r * 512 + t;
    int rr = idx >> 5;
    if (row0 + rr < N) o4p[idx] = *(const float4*)&aggT[rr][(idx & 31) * 4];
  }
}

extern "C" void kernel_launch(void* const* d_in, const int* in_sizes, int n_in,
                              void* d_out, int out_size, void* d_ws, size_t ws_size,
                              hipStream_t stream) {
  const float* x   = (const float*)d_in[0];
  const int* src   = (const int*)d_in[1];
  const int* dst   = (const int*)d_in[2];
  const float* W   = (const float*)d_in[3];
  const float* b   = (const float*)d_in[4];
  const float* fcW = (const float*)d_in[5];
  const float* fcb = (const float*)d_in[6];
  float* out = (float*)d_out;

  const int N = in_sizes[0] / 128;
  const int E = in_sizes[1];

  // ws layout (ints), NA = N rounded up to 1024
  const int NA = ((N + 1023) / 1024) * 1024;
  int* wsi = (int*)d_ws;
  int*   cursor   = wsi + 0 * (size_t)NA;          // becomes deg_in
  int*   deg_out  = wsi + 1 * (size_t)NA;
  float* norm_src = (float*)(wsi + 2 * (size_t)NA);
  float* norm_dst = (float*)(wsi + 3 * (size_t)NA);
  float* fcwT     = (float*)(wsi + 4 * (size_t)NA);        // 16384 floats
  int*   bucket   = wsi + 4 * (size_t)NA + 16384;          // N*64 ints (25.6MB)

  // 0. zero cursor + deg_out (contiguous 2*NA ints)
  zero_kernel<<<256, 256, 0, stream>>>(wsi, 2 * NA);
  // T. fcwT = fcW^T
  transpose128_kernel<<<64, 256, 0, stream>>>(fcW, fcwT);
  // 1. one-pass degree count + bucket fill
  fill_deg_kernel<<<(E / 4 + 255) / 256, 256, 0, stream>>>(src, dst, deg_out, cursor,
                                                           bucket, E);
  // 2. norms
  norm_kernel<<<(N + 255) / 256, 256, 0, stream>>>(deg_out, cursor, norm_src, norm_dst, N);
  // 3. aggregate: one wave per node -> d_out holds normalized agg
  agg_kernel<<<(N + 3) / 4, 256, 0, stream>>>(x, bucket, cursor,
                                              norm_src, norm_dst, out, N);
  // 4. fused GEMMs in-place on d_out (64-row tiles)
  gemm_fused_kernel<<<(N + 63) / 64, 512, 0, stream>>>(out, W, b, fcwT, fcb, N);
}

// Round 7
// 456.217 us; speedup vs baseline: 1.4275x; 1.0760x over previous
//
#include <hip/hip_runtime.h>

// ---------------------------------------------------------------------------
// NGNN GCNConv: out = relu((norm_dst * segsum_dst((x*norm_src)[src])) @ W + b) @ fc_W^T + fc_b
// N=100000 nodes, E=1600000 edges, D=128.
//
// R6: dst-side grouping via LDS-binned counting sort (dense writes) instead
// of per-edge cursor atomics + scattered bucket stores (was 102 MB of
// scattered 32B-sector traffic; now ~35 MB mostly dense + ~150k atomics).
// src-side degree histogram stays atomic (51 MB, cheaper than sorting).
//
//   0. zero deg_out + binCnt
//   T. transpose fc_W -> fcwT
//   1. deg_out histogram (int4, atomic)
//   2. bin_count: LDS hist of dst>>9 (196 bins) -> binCnt
//   3. bin_scan: exclusive scan -> binOff, binCursor
//   4. bin_scatter: per 4096-edge block: LDS hist -> claim region per bin
//      (1 atomic per block-bin) -> scatter packed (s | dlocal<<17)
//   5. bin_process: 1 block per bin: LDS hist512+scan -> csr_off/deg_in,
//      dense scatter of src ids into csr_src
//   6. norm; 7. agg (1 wave/node, 4-way unroll); 8. gemm_fused (scalar-pipe
//      weights, s_load broadcast -- R3 win)
// ---------------------------------------------------------------------------

#define BIN_SHIFT 9
#define BIN_RANGE 512

__global__ void zero_kernel(int* __restrict__ p, int n) {
  int i = blockIdx.x * blockDim.x + threadIdx.x;
  int stride = gridDim.x * blockDim.x;
  for (; i < n; i += stride) p[i] = 0;
}

// fcwT[k][j] = fcW[j][k], 128x128
__global__ void transpose128_kernel(const float* __restrict__ in, float* __restrict__ out) {
  int idx = blockIdx.x * 256 + threadIdx.x;  // 0..16383
  int k = idx >> 7, j = idx & 127;
  out[idx] = in[j * 128 + k];
}

// src out-degree histogram, 4 edges/thread via int4
__global__ void deg_out_kernel(const int* __restrict__ src, int* __restrict__ deg_out, int E) {
  int i = blockIdx.x * blockDim.x + threadIdx.x;
  int e0 = i * 4;
  if (e0 + 3 < E) {
    int4 s4 = *(const int4*)&src[e0];
    atomicAdd(&deg_out[s4.x], 1);
    atomicAdd(&deg_out[s4.y], 1);
    atomicAdd(&deg_out[s4.z], 1);
    atomicAdd(&deg_out[s4.w], 1);
  } else {
    for (int e = e0; e < E; ++e) atomicAdd(&deg_out[src[e]], 1);
  }
}

// coarse histogram of dst bins (B <= 256)
__global__ __launch_bounds__(256) void bin_count_kernel(const int* __restrict__ dst,
                                                        int* __restrict__ binCnt, int E, int B) {
  __shared__ int h[256];
  int t = threadIdx.x;
  h[t] = 0;
  __syncthreads();
  int i = blockIdx.x * blockDim.x + t;
  int stride = gridDim.x * blockDim.x;
  for (; i < E; i += stride) atomicAdd(&h[dst[i] >> BIN_SHIFT], 1);
  __syncthreads();
  if (t < B && h[t]) atomicAdd(&binCnt[t], h[t]);
}

// single block: exclusive scan of binCnt -> binOff (B+1), init binCursor
__global__ __launch_bounds__(256) void bin_scan_kernel(const int* __restrict__ binCnt,
                                                       int* __restrict__ binOff,
                                                       int* __restrict__ binCursor, int B) {
  __shared__ int s[256];
  int t = threadIdx.x;
  int v = (t < B) ? binCnt[t] : 0;
  s[t] = v;
  __syncthreads();
  for (int off = 1; off < 256; off <<= 1) {
    int a = (t >= off) ? s[t - off] : 0;
    __syncthreads();
    s[t] += a;
    __syncthreads();
  }
  int excl = s[t] - v;
  if (t < B) { binOff[t] = excl; binCursor[t] = excl; }
  if (t == B - 1) binOff[B] = excl + v;
}

// per-4096-edge block: local bin hist, claim contiguous region per (block,bin),
// scatter packed entries (s | dlocal<<17). Writes confined to small hot regions.
__global__ __launch_bounds__(256) void bin_scatter_kernel(
    const int* __restrict__ src, const int* __restrict__ dst,
    int* __restrict__ binCursor, int* __restrict__ packed, int E, int B) {
  __shared__ int h[256];
  __shared__ int base[256];
  int t = threadIdx.x;
  int e0 = blockIdx.x * 4096;
  int eend = e0 + 4096 < E ? e0 + 4096 : E;
  h[t] = 0;
  __syncthreads();
  for (int e = e0 + t; e < eend; e += 256) atomicAdd(&h[dst[e] >> BIN_SHIFT], 1);
  __syncthreads();
  if (t < B) base[t] = h[t] ? atomicAdd(&binCursor[t], h[t]) : 0;
  __syncthreads();
  h[t] = 0;  // reuse as local cursor
  __syncthreads();
  for (int e = e0 + t; e < eend; e += 256) {
    int d = dst[e], s = src[e];
    int bin = d >> BIN_SHIFT;
    int p = atomicAdd(&h[bin], 1);
    packed[base[bin] + p] = s | ((d & (BIN_RANGE - 1)) << 17);
  }
}

// one block per bin: exact per-node offsets via LDS hist512 + scan,
// dense scatter of src ids into csr_src; writes csr_off + deg_in.
__global__ __launch_bounds__(256) void bin_process_kernel(
    const int* __restrict__ packed, const int* __restrict__ binOff,
    int* __restrict__ csr_src, int* __restrict__ csr_off, int* __restrict__ deg_in, int N) {
  __shared__ int h[512];
  __shared__ int p2[256];
  int b = blockIdx.x, t = threadIdx.x;
  int lo = binOff[b], hi = binOff[b + 1];
  h[t] = 0; h[t + 256] = 0;
  __syncthreads();
  for (int i = lo + t; i < hi; i += 256) atomicAdd(&h[(packed[i] >> 17) & 511], 1);
  __syncthreads();
  int c0 = h[2 * t], c1 = h[2 * t + 1];
  int pair = c0 + c1;
  p2[t] = pair;
  __syncthreads();
  for (int off = 1; off < 256; off <<= 1) {
    int a = (t >= off) ? p2[t - off] : 0;
    __syncthreads();
    p2[t] += a;
    __syncthreads();
  }
  int epair = p2[t] - pair;  // exclusive base of this pair
  int o0 = lo + epair, o1 = lo + epair + c0;
  int n0 = b * BIN_RANGE + 2 * t, n1 = n0 + 1;
  if (n0 < N) { csr_off[n0] = o0; deg_in[n0] = c0; }
  if (n1 < N) { csr_off[n1] = o1; deg_in[n1] = c1; }
  __syncthreads();
  h[2 * t] = o0;       // reuse as global cursors
  h[2 * t + 1] = o1;
  __syncthreads();
  for (int i = lo + t; i < hi; i += 256) {
    int pk = packed[i];
    int pos = atomicAdd(&h[(pk >> 17) & 511], 1);
    csr_src[pos] = pk & 0x1FFFF;
  }
}

__global__ void norm_kernel(const int* __restrict__ deg_out, const int* __restrict__ deg_in,
                            float* __restrict__ norm_src, float* __restrict__ norm_dst, int N) {
  int i = blockIdx.x * blockDim.x + threadIdx.x;
  if (i < N) {
    int dgo = deg_out[i]; if (dgo < 1) dgo = 1;
    int dgi = deg_in[i];  if (dgi < 1) dgi = 1;
    norm_src[i] = 1.0f / sqrtf((float)dgo);
    norm_dst[i] = 1.0f / sqrtf((float)dgi);
  }
}

// 1 wave per dst node; lane holds float2 of the 128-wide row.
// 4-way edge unroll: 4 independent index/norm/row loads in flight per wave.
__global__ __launch_bounds__(256) void agg_kernel(
    const float* __restrict__ x, const int* __restrict__ csr_src,
    const int* __restrict__ csr_off, const int* __restrict__ deg_in,
    const float* __restrict__ norm_src, const float* __restrict__ norm_dst,
    float* __restrict__ out, int N) {
  int wid = threadIdx.x >> 6;
  int lane = threadIdx.x & 63;
  int v = blockIdx.x * 4 + wid;
  if (v >= N) return;
  int start = csr_off[v];
  int cnt = deg_in[v];
  int end = start + cnt;
  const float2* __restrict__ x2 = (const float2*)x;

  float2 a0, a1, a2, a3;
  a0.x = a0.y = a1.x = a1.y = a2.x = a2.y = a3.x = a3.y = 0.f;

  int e = start;
  for (; e + 4 <= end; e += 4) {
    int s0 = csr_src[e + 0];
    int s1 = csr_src[e + 1];
    int s2 = csr_src[e + 2];
    int s3 = csr_src[e + 3];
    float n0 = norm_src[s0];
    float n1 = norm_src[s1];
    float n2 = norm_src[s2];
    float n3 = norm_src[s3];
    float2 v0 = x2[(size_t)s0 * 64 + lane];
    float2 v1 = x2[(size_t)s1 * 64 + lane];
    float2 v2 = x2[(size_t)s2 * 64 + lane];
    float2 v3 = x2[(size_t)s3 * 64 + lane];
    a0.x += v0.x * n0; a0.y += v0.y * n0;
    a1.x += v1.x * n1; a1.y += v1.y * n1;
    a2.x += v2.x * n2; a2.y += v2.y * n2;
    a3.x += v3.x * n3; a3.y += v3.y * n3;
  }
  for (; e < end; ++e) {
    int s = csr_src[e];
    float n = norm_src[s];
    float2 xv = x2[(size_t)s * 64 + lane];
    a0.x += xv.x * n; a0.y += xv.y * n;
  }

  float nd = norm_dst[v];
  float2 r;
  r.x = ((a0.x + a1.x) + (a2.x + a3.x)) * nd;
  r.y = ((a0.y + a1.y) + (a2.y + a3.y)) * nd;
  ((float2*)out)[(size_t)v * 64 + lane] = r;
}

// Fused double-GEMM, in-place on io. 64-row tile, 512 threads (8 waves).
// lane = row (0..63); wave w owns columns [16w, 16w+16).
// Weights via wave-uniform scalar loads (SMEM pipe + SGPR-broadcast FMA).
__global__ __launch_bounds__(512) void gemm_fused_kernel(
    float* __restrict__ io, const float* __restrict__ W, const float* __restrict__ b,
    const float* __restrict__ fcwT, const float* __restrict__ fcb, int N) {
  __shared__ float aggT[64][132];
  __shared__ float hT[64][132];

  int t = threadIdx.x;
  int lane = t & 63;
  int wave = __builtin_amdgcn_readfirstlane(t >> 6);  // force wave-uniform
  int j0 = wave * 16;
  int row0 = blockIdx.x * 64;
  size_t base = (size_t)row0 * 128;

  // stage 64x128 agg tile (coalesced float4)
  const float4* __restrict__ io4 = (const float4*)(io + base);
#pragma unroll
  for (int r = 0; r < 4; ++r) {
    int idx = r * 512 + t;       // float4 index in tile, 0..2047
    int rr = idx >> 5;           // row (32 float4 per row)
    float4 v = make_float4(0.f, 0.f, 0.f, 0.f);
    if (row0 + rr < N) v = io4[idx];
    *(float4*)&aggT[rr][(idx & 31) * 4] = v;
  }
  __syncthreads();

  // ---- phase 1: hT[lane][j0..j0+15] = relu(aggT[lane][:] @ W[:, j0..j0+15] + b)
  {
    float acc[16];
#pragma unroll
    for (int q = 0; q < 4; ++q) {
      float4 b4 = *(const float4*)&b[j0 + 4 * q];   // uniform -> s_load
      acc[4 * q + 0] = b4.x; acc[4 * q + 1] = b4.y;
      acc[4 * q + 2] = b4.z; acc[4 * q + 3] = b4.w;
    }
#pragma unroll 4
    for (int k4 = 0; k4 < 32; ++k4) {
      float4 a4 = *(const float4*)&aggT[lane][k4 * 4];
#pragma unroll
      for (int kk = 0; kk < 4; ++kk) {
        float av = (kk == 0) ? a4.x : (kk == 1) ? a4.y : (kk == 2) ? a4.z : a4.w;
        const float* Wrow = &W[(size_t)(k4 * 4 + kk) * 128 + j0];  // uniform
#pragma unroll
        for (int q = 0; q < 4; ++q) {
          float4 w4 = *(const float4*)&Wrow[4 * q];  // s_load_dwordx4
          acc[4 * q + 0] += av * w4.x;
          acc[4 * q + 1] += av * w4.y;
          acc[4 * q + 2] += av * w4.z;
          acc[4 * q + 3] += av * w4.w;
        }
      }
    }
#pragma unroll
    for (int q = 0; q < 4; ++q) {
      float4 h4;
      h4.x = fmaxf(acc[4 * q + 0], 0.f);
      h4.y = fmaxf(acc[4 * q + 1], 0.f);
      h4.z = fmaxf(acc[4 * q + 2], 0.f);
      h4.w = fmaxf(acc[4 * q + 3], 0.f);
      *(float4*)&hT[lane][j0 + 4 * q] = h4;
    }
  }
  __syncthreads();

  // ---- phase 2: out[lane][j0..j0+15] = hT[lane][:] @ fcwT[:, j0..j0+15] + fcb
  {
    float acc[16];
#pragma unroll
    for (int q = 0; q < 4; ++q) {
      float4 b4 = *(const float4*)&fcb[j0 + 4 * q];
      acc[4 * q + 0] = b4.x; acc[4 * q + 1] = b4.y;
      acc[4 * q + 2] = b4.z; acc[4 * q + 3] = b4.w;
    }
#pragma unroll 4
    for (int k4 = 0; k4 < 32; ++k4) {
      float4 a4 = *(const float4*)&hT[lane][k4 * 4];
#pragma unroll
      for (int kk = 0; kk < 4; ++kk) {
        float av = (kk == 0) ? a4.x : (kk == 1) ? a4.y : (kk == 2) ? a4.z : a4.w;
        const float* Wrow = &fcwT[(size_t)(k4 * 4 + kk) * 128 + j0];
#pragma unroll
        for (int q = 0; q < 4; ++q) {
          float4 w4 = *(const float4*)&Wrow[4 * q];
          acc[4 * q + 0] += av * w4.x;
          acc[4 * q + 1] += av * w4.y;
          acc[4 * q + 2] += av * w4.z;
          acc[4 * q + 3] += av * w4.w;
        }
      }
    }
    // stage result into aggT (free after phase 1) for coalesced store
#pragma unroll
    for (int q = 0; q < 4; ++q) {
      float4 o4;
      o4.x = acc[4 * q + 0]; o4.y = acc[4 * q + 1];
      o4.z = acc[4 * q + 2]; o4.w = acc[4 * q + 3];
      *(float4*)&aggT[lane][j0 + 4 * q] = o4;
    }
  }
  __syncthreads();

  // coalesced copy-out
  float4* __restrict__ o4p = (float4*)(io + base);
#pragma unroll
  for (int r = 0; r < 4; ++r) {
    int idx = r * 512 + t;
    int rr = idx >> 5;
    if (row0 + rr < N) o4p[idx] = *(const float4*)&aggT[rr][(idx & 31) * 4];
  }
}

extern "C" void kernel_launch(void* const* d_in, const int* in_sizes, int n_in,
                              void* d_out, int out_size, void* d_ws, size_t ws_size,
                              hipStream_t stream) {
  const float* x   = (const float*)d_in[0];
  const int* src   = (const int*)d_in[1];
  const int* dst   = (const int*)d_in[2];
  const float* W   = (const float*)d_in[3];
  const float* b   = (const float*)d_in[4];
  const float* fcW = (const float*)d_in[5];
  const float* fcb = (const float*)d_in[6];
  float* out = (float*)d_out;

  const int N = in_sizes[0] / 128;
  const int E = in_sizes[1];
  const int B = (N + BIN_RANGE - 1) / BIN_RANGE;   // 196 bins (<=256)

  // ws layout (ints), NA = N rounded up to 1024
  const int NA = ((N + 1023) / 1024) * 1024;
  int* wsi = (int*)d_ws;
  int*   deg_out_a = wsi + 0 * (size_t)NA;         // [NA]
  int*   binCnt    = wsi + 1 * (size_t)NA;         // [256]  (zeroed with deg_out)
  int*   binOff    = binCnt + 256;                 // [257]
  int*   binCursor = binOff + 257;                 // [256]
  int*   deg_in    = wsi + 2 * (size_t)NA;
  int*   csr_off   = wsi + 3 * (size_t)NA;
  float* norm_src  = (float*)(wsi + 4 * (size_t)NA);
  float* norm_dst  = (float*)(wsi + 5 * (size_t)NA);
  float* fcwT      = (float*)(wsi + 6 * (size_t)NA);        // 16384 floats
  int*   packed    = wsi + 6 * (size_t)NA + 16384;          // [E]
  int*   csr_src   = packed + E;                            // [E]

  // 0. zero deg_out + binCnt (contiguous NA+256 ints)
  zero_kernel<<<256, 256, 0, stream>>>(wsi, NA + 256);
  // T. fcwT = fcW^T
  transpose128_kernel<<<64, 256, 0, stream>>>(fcW, fcwT);
  // 1. src out-degree histogram (atomic)
  deg_out_kernel<<<(E / 4 + 255) / 256, 256, 0, stream>>>(src, deg_out_a, E);
  // 2-5. dst-side counting sort -> csr_src grouped by dst, csr_off, deg_in
  bin_count_kernel<<<512, 256, 0, stream>>>(dst, binCnt, E, B);
  bin_scan_kernel<<<1, 256, 0, stream>>>(binCnt, binOff, binCursor, B);
  bin_scatter_kernel<<<(E + 4095) / 4096, 256, 0, stream>>>(src, dst, binCursor, packed, E, B);
  bin_process_kernel<<<B, 256, 0, stream>>>(packed, binOff, csr_src, csr_off, deg_in, N);
  // 6. norms
  norm_kernel<<<(N + 255) / 256, 256, 0, stream>>>(deg_out_a, deg_in, norm_src, norm_dst, N);
  // 7. aggregate: one wave per node -> d_out holds normalized agg
  agg_kernel<<<(N + 3) / 4, 256, 0, stream>>>(x, csr_src, csr_off, deg_in,
                                              norm_src, norm_dst, out, N);
  // 8. fused GEMMs in-place on d_out (64-row tiles)
  gemm_fused_kernel<<<(N + 63) / 64, 512, 0, stream>>>(out, W, b, fcwT, fcb, N);
}

// Round 8
// 399.099 us; speedup vs baseline: 1.6318x; 1.1431x over previous
//
#include <hip/hip_runtime.h>
#include <hip/hip_fp16.h>

// ---------------------------------------------------------------------------
// NGNN GCNConv: out = relu((norm_dst * segsum_dst((x*norm_src)[src])) @ W + b) @ fc_W^T + fc_b
// N=100000, E=1600000, D=128.
//
// R8: (a) agg gathers FP16 pre-scaled rows (256B/edge instead of 512B+norm):
//     the 3.7 TB/s random-gather fabric ceiling is byte-limited, so halving
//     bytes halves agg time. fp32 accumulate; fp16 adds ~1e-4 absmax.
//     (b) deg_out by counting-sort histogram (reuses bin machinery + packed
//     buffer) replacing 1.6M scattered atomic RMWs (~51MB of 32B sectors).
//
//   0. zero deg_out/binCnt/srcBinCnt
//   T. transpose fc_W -> fcwT
//   1. bin_count2: LDS hists of dst>>9 and src>>9
//   2. bin_scan2: both exclusive scans -> offsets/cursors
//   3. bin_scatter (dst) -> packed(s|dlocal<<17)
//   4. bin_process (dst) -> csr_src, csr_off, deg_in   [frees packed]
//   5. bin_scatter_src -> packed (s&511)
//   6. bin_process_src -> deg_out (LDS hist, no atomics to HBM)
//   7. norm; 8. prescale xs=fp16(x*norm_src); 9. agg (fp16 gather, 8-way)
//  10. gemm_fused (scalar-pipe weights -- R3 win)
// ---------------------------------------------------------------------------

#define BIN_SHIFT 9
#define BIN_RANGE 512

__global__ void zero_kernel(int* __restrict__ p, int n) {
  int i = blockIdx.x * blockDim.x + threadIdx.x;
  int stride = gridDim.x * blockDim.x;
  for (; i < n; i += stride) p[i] = 0;
}

// fcwT[k][j] = fcW[j][k], 128x128
__global__ void transpose128_kernel(const float* __restrict__ in, float* __restrict__ out) {
  int idx = blockIdx.x * 256 + threadIdx.x;  // 0..16383
  int k = idx >> 7, j = idx & 127;
  out[idx] = in[j * 128 + k];
}

// coarse histograms of dst and src bins (B <= 256), one pass over edges
__global__ __launch_bounds__(256) void bin_count2_kernel(
    const int* __restrict__ src, const int* __restrict__ dst,
    int* __restrict__ binCnt, int* __restrict__ srcBinCnt, int E, int B) {
  __shared__ int hd[256];
  __shared__ int hs[256];
  int t = threadIdx.x;
  hd[t] = 0; hs[t] = 0;
  __syncthreads();
  int i = blockIdx.x * blockDim.x + t;
  int stride = gridDim.x * blockDim.x;
  for (; i < E; i += stride) {
    atomicAdd(&hd[dst[i] >> BIN_SHIFT], 1);
    atomicAdd(&hs[src[i] >> BIN_SHIFT], 1);
  }
  __syncthreads();
  if (t < B) {
    if (hd[t]) atomicAdd(&binCnt[t], hd[t]);
    if (hs[t]) atomicAdd(&srcBinCnt[t], hs[t]);
  }
}

// single block: exclusive scans of binCnt and srcBinCnt
__global__ __launch_bounds__(256) void bin_scan2_kernel(
    const int* __restrict__ binCnt, int* __restrict__ binOff, int* __restrict__ binCursor,
    const int* __restrict__ srcBinCnt, int* __restrict__ srcBinOff,
    int* __restrict__ srcBinCursor, int B) {
  __shared__ int s[256];
  int t = threadIdx.x;
  // scan 1: dst bins
  int v = (t < B) ? binCnt[t] : 0;
  s[t] = v;
  __syncthreads();
  for (int off = 1; off < 256; off <<= 1) {
    int a = (t >= off) ? s[t - off] : 0;
    __syncthreads();
    s[t] += a;
    __syncthreads();
  }
  int excl = s[t] - v;
  if (t < B) { binOff[t] = excl; binCursor[t] = excl; }
  if (t == B - 1) binOff[B] = excl + v;
  __syncthreads();
  // scan 2: src bins
  v = (t < B) ? srcBinCnt[t] : 0;
  s[t] = v;
  __syncthreads();
  for (int off = 1; off < 256; off <<= 1) {
    int a = (t >= off) ? s[t - off] : 0;
    __syncthreads();
    s[t] += a;
    __syncthreads();
  }
  excl = s[t] - v;
  if (t < B) { srcBinOff[t] = excl; srcBinCursor[t] = excl; }
  if (t == B - 1) srcBinOff[B] = excl + v;
}

// per-4096-edge block: local bin hist, claim contiguous region per (block,bin),
// scatter packed entries (s | dlocal<<17). Writes confined to small hot regions.
__global__ __launch_bounds__(256) void bin_scatter_kernel(
    const int* __restrict__ src, const int* __restrict__ dst,
    int* __restrict__ binCursor, int* __restrict__ packed, int E, int B) {
  __shared__ int h[256];
  __shared__ int base[256];
  int t = threadIdx.x;
  int e0 = blockIdx.x * 4096;
  int eend = e0 + 4096 < E ? e0 + 4096 : E;
  h[t] = 0;
  __syncthreads();
  for (int e = e0 + t; e < eend; e += 256) atomicAdd(&h[dst[e] >> BIN_SHIFT], 1);
  __syncthreads();
  if (t < B) base[t] = h[t] ? atomicAdd(&binCursor[t], h[t]) : 0;
  __syncthreads();
  h[t] = 0;  // reuse as local cursor
  __syncthreads();
  for (int e = e0 + t; e < eend; e += 256) {
    int d = dst[e], s = src[e];
    int bin = d >> BIN_SHIFT;
    int p = atomicAdd(&h[bin], 1);
    packed[base[bin] + p] = s | ((d & (BIN_RANGE - 1)) << 17);
  }
}

// one block per bin: exact per-node offsets via LDS hist512 + scan,
// dense scatter of src ids into csr_src; writes csr_off + deg_in.
__global__ __launch_bounds__(256) void bin_process_kernel(
    const int* __restrict__ packed, const int* __restrict__ binOff,
    int* __restrict__ csr_src, int* __restrict__ csr_off, int* __restrict__ deg_in, int N) {
  __shared__ int h[512];
  __shared__ int p2[256];
  int b = blockIdx.x, t = threadIdx.x;
  int lo = binOff[b], hi = binOff[b + 1];
  h[t] = 0; h[t + 256] = 0;
  __syncthreads();
  for (int i = lo + t; i < hi; i += 256) atomicAdd(&h[(packed[i] >> 17) & 511], 1);
  __syncthreads();
  int c0 = h[2 * t], c1 = h[2 * t + 1];
  int pair = c0 + c1;
  p2[t] = pair;
  __syncthreads();
  for (int off = 1; off < 256; off <<= 1) {
    int a = (t >= off) ? p2[t - off] : 0;
    __syncthreads();
    p2[t] += a;
    __syncthreads();
  }
  int epair = p2[t] - pair;  // exclusive base of this pair
  int o0 = lo + epair, o1 = lo + epair + c0;
  int n0 = b * BIN_RANGE + 2 * t, n1 = n0 + 1;
  if (n0 < N) { csr_off[n0] = o0; deg_in[n0] = c0; }
  if (n1 < N) { csr_off[n1] = o1; deg_in[n1] = c1; }
  __syncthreads();
  h[2 * t] = o0;       // reuse as global cursors
  h[2 * t + 1] = o1;
  __syncthreads();
  for (int i = lo + t; i < hi; i += 256) {
    int pk = packed[i];
    int pos = atomicAdd(&h[(pk >> 17) & 511], 1);
    csr_src[pos] = pk & 0x1FFFF;
  }
}

// same binning trick on src; payload = local node id only
__global__ __launch_bounds__(256) void bin_scatter_src_kernel(
    const int* __restrict__ src, int* __restrict__ srcBinCursor,
    int* __restrict__ packed, int E, int B) {
  __shared__ int h[256];
  __shared__ int base[256];
  int t = threadIdx.x;
  int e0 = blockIdx.x * 4096;
  int eend = e0 + 4096 < E ? e0 + 4096 : E;
  h[t] = 0;
  __syncthreads();
  for (int e = e0 + t; e < eend; e += 256) atomicAdd(&h[src[e] >> BIN_SHIFT], 1);
  __syncthreads();
  if (t < B) base[t] = h[t] ? atomicAdd(&srcBinCursor[t], h[t]) : 0;
  __syncthreads();
  h[t] = 0;
  __syncthreads();
  for (int e = e0 + t; e < eend; e += 256) {
    int s = src[e];
    int bin = s >> BIN_SHIFT;
    int p = atomicAdd(&h[bin], 1);
    packed[base[bin] + p] = s & (BIN_RANGE - 1);
  }
}

// one block per bin: LDS hist -> deg_out (no scan, no scatter-back)
__global__ __launch_bounds__(256) void bin_process_src_kernel(
    const int* __restrict__ packed, const int* __restrict__ srcBinOff,
    int* __restrict__ deg_out, int N) {
  __shared__ int h[512];
  int b = blockIdx.x, t = threadIdx.x;
  int lo = srcBinOff[b], hi = srcBinOff[b + 1];
  h[t] = 0; h[t + 256] = 0;
  __syncthreads();
  for (int i = lo + t; i < hi; i += 256) atomicAdd(&h[packed[i] & 511], 1);
  __syncthreads();
  int n0 = b * BIN_RANGE + t, n1 = n0 + 256;
  if (n0 < N) deg_out[n0] = h[t];
  if (n1 < N) deg_out[n1] = h[t + 256];
}

__global__ void norm_kernel(const int* __restrict__ deg_out, const int* __restrict__ deg_in,
                            float* __restrict__ norm_src, float* __restrict__ norm_dst, int N) {
  int i = blockIdx.x * blockDim.x + threadIdx.x;
  if (i < N) {
    int dgo = deg_out[i]; if (dgo < 1) dgo = 1;
    int dgi = deg_in[i];  if (dgi < 1) dgi = 1;
    norm_src[i] = 1.0f / sqrtf((float)dgo);
    norm_dst[i] = 1.0f / sqrtf((float)dgi);
  }
}

// xs2[i] = fp16(x2[i] * norm_src[i>>6]); i indexes half2/float2 pairs
__global__ void prescale_kernel(const float2* __restrict__ x2, const float* __restrict__ ns,
                                __half2* __restrict__ xs2, int n64) {
  int i = blockIdx.x * blockDim.x + threadIdx.x;
  int stride = gridDim.x * blockDim.x;
  for (; i < n64; i += stride) {
    float2 v = x2[i];
    float nn = ns[i >> 6];
    xs2[i] = __floats2half2_rn(v.x * nn, v.y * nn);
  }
}

// 1 wave per dst node; lane holds half2 (2 feats) of the 128-wide row.
// 8-way edge unroll: 8 independent 256B row gathers in flight.
__global__ __launch_bounds__(256) void agg_kernel(
    const __half2* __restrict__ xs2, const int* __restrict__ csr_src,
    const int* __restrict__ csr_off, const int* __restrict__ deg_in,
    const float* __restrict__ norm_dst, float* __restrict__ out, int N) {
  int wid = threadIdx.x >> 6;
  int lane = threadIdx.x & 63;
  int v = blockIdx.x * 4 + wid;
  if (v >= N) return;
  int start = csr_off[v];
  int cnt = deg_in[v];
  int end = start + cnt;

  float2 a0, a1, a2, a3, a4, a5, a6, a7;
  a0.x = a0.y = a1.x = a1.y = a2.x = a2.y = a3.x = a3.y = 0.f;
  a4.x = a4.y = a5.x = a5.y = a6.x = a6.y = a7.x = a7.y = 0.f;

  int e = start;
  for (; e + 8 <= end; e += 8) {
    int s0 = csr_src[e + 0];
    int s1 = csr_src[e + 1];
    int s2 = csr_src[e + 2];
    int s3 = csr_src[e + 3];
    int s4 = csr_src[e + 4];
    int s5 = csr_src[e + 5];
    int s6 = csr_src[e + 6];
    int s7 = csr_src[e + 7];
    float2 f0 = __half22float2(xs2[(size_t)s0 * 64 + lane]);
    float2 f1 = __half22float2(xs2[(size_t)s1 * 64 + lane]);
    float2 f2 = __half22float2(xs2[(size_t)s2 * 64 + lane]);
    float2 f3 = __half22float2(xs2[(size_t)s3 * 64 + lane]);
    float2 f4 = __half22float2(xs2[(size_t)s4 * 64 + lane]);
    float2 f5 = __half22float2(xs2[(size_t)s5 * 64 + lane]);
    float2 f6 = __half22float2(xs2[(size_t)s6 * 64 + lane]);
    float2 f7 = __half22float2(xs2[(size_t)s7 * 64 + lane]);
    a0.x += f0.x; a0.y += f0.y;
    a1.x += f1.x; a1.y += f1.y;
    a2.x += f2.x; a2.y += f2.y;
    a3.x += f3.x; a3.y += f3.y;
    a4.x += f4.x; a4.y += f4.y;
    a5.x += f5.x; a5.y += f5.y;
    a6.x += f6.x; a6.y += f6.y;
    a7.x += f7.x; a7.y += f7.y;
  }
  if (e + 4 <= end) {
    int s0 = csr_src[e + 0];
    int s1 = csr_src[e + 1];
    int s2 = csr_src[e + 2];
    int s3 = csr_src[e + 3];
    float2 f0 = __half22float2(xs2[(size_t)s0 * 64 + lane]);
    float2 f1 = __half22float2(xs2[(size_t)s1 * 64 + lane]);
    float2 f2 = __half22float2(xs2[(size_t)s2 * 64 + lane]);
    float2 f3 = __half22float2(xs2[(size_t)s3 * 64 + lane]);
    a0.x += f0.x; a0.y += f0.y;
    a1.x += f1.x; a1.y += f1.y;
    a2.x += f2.x; a2.y += f2.y;
    a3.x += f3.x; a3.y += f3.y;
    e += 4;
  }
  for (; e < end; ++e) {
    int s = csr_src[e];
    float2 f = __half22float2(xs2[(size_t)s * 64 + lane]);
    a0.x += f.x; a0.y += f.y;
  }

  float nd = norm_dst[v];
  float2 r;
  r.x = (((a0.x + a1.x) + (a2.x + a3.x)) + ((a4.x + a5.x) + (a6.x + a7.x))) * nd;
  r.y = (((a0.y + a1.y) + (a2.y + a3.y)) + ((a4.y + a5.y) + (a6.y + a7.y))) * nd;
  ((float2*)out)[(size_t)v * 64 + lane] = r;
}

// Fused double-GEMM, in-place on io. 64-row tile, 512 threads (8 waves).
// lane = row (0..63); wave w owns columns [16w, 16w+16).
// Weights via wave-uniform scalar loads (SMEM pipe + SGPR-broadcast FMA).
__global__ __launch_bounds__(512) void gemm_fused_kernel(
    float* __restrict__ io, const float* __restrict__ W, const float* __restrict__ b,
    const float* __restrict__ fcwT, const float* __restrict__ fcb, int N) {
  __shared__ float aggT[64][132];
  __shared__ float hT[64][132];

  int t = threadIdx.x;
  int lane = t & 63;
  int wave = __builtin_amdgcn_readfirstlane(t >> 6);  // force wave-uniform
  int j0 = wave * 16;
  int row0 = blockIdx.x * 64;
  size_t base = (size_t)row0 * 128;

  // stage 64x128 agg tile (coalesced float4)
  const float4* __restrict__ io4 = (const float4*)(io + base);
#pragma unroll
  for (int r = 0; r < 4; ++r) {
    int idx = r * 512 + t;       // float4 index in tile, 0..2047
    int rr = idx >> 5;           // row (32 float4 per row)
    float4 v = make_float4(0.f, 0.f, 0.f, 0.f);
    if (row0 + rr < N) v = io4[idx];
    *(float4*)&aggT[rr][(idx & 31) * 4] = v;
  }
  __syncthreads();

  // ---- phase 1: hT[lane][j0..j0+15] = relu(aggT[lane][:] @ W[:, j0..j0+15] + b)
  {
    float acc[16];
#pragma unroll
    for (int q = 0; q < 4; ++q) {
      float4 b4 = *(const float4*)&b[j0 + 4 * q];   // uniform -> s_load
      acc[4 * q + 0] = b4.x; acc[4 * q + 1] = b4.y;
      acc[4 * q + 2] = b4.z; acc[4 * q + 3] = b4.w;
    }
#pragma unroll 4
    for (int k4 = 0; k4 < 32; ++k4) {
      float4 a4 = *(const float4*)&aggT[lane][k4 * 4];
#pragma unroll
      for (int kk = 0; kk < 4; ++kk) {
        float av = (kk == 0) ? a4.x : (kk == 1) ? a4.y : (kk == 2) ? a4.z : a4.w;
        const float* Wrow = &W[(size_t)(k4 * 4 + kk) * 128 + j0];  // uniform
#pragma unroll
        for (int q = 0; q < 4; ++q) {
          float4 w4 = *(const float4*)&Wrow[4 * q];  // s_load_dwordx4
          acc[4 * q + 0] += av * w4.x;
          acc[4 * q + 1] += av * w4.y;
          acc[4 * q + 2] += av * w4.z;
          acc[4 * q + 3] += av * w4.w;
        }
      }
    }
#pragma unroll
    for (int q = 0; q < 4; ++q) {
      float4 h4;
      h4.x = fmaxf(acc[4 * q + 0], 0.f);
      h4.y = fmaxf(acc[4 * q + 1], 0.f);
      h4.z = fmaxf(acc[4 * q + 2], 0.f);
      h4.w = fmaxf(acc[4 * q + 3], 0.f);
      *(float4*)&hT[lane][j0 + 4 * q] = h4;
    }
  }
  __syncthreads();

  // ---- phase 2: out[lane][j0..j0+15] = hT[lane][:] @ fcwT[:, j0..j0+15] + fcb
  {
    float acc[16];
#pragma unroll
    for (int q = 0; q < 4; ++q) {
      float4 b4 = *(const float4*)&fcb[j0 + 4 * q];
      acc[4 * q + 0] = b4.x; acc[4 * q + 1] = b4.y;
      acc[4 * q + 2] = b4.z; acc[4 * q + 3] = b4.w;
    }
#pragma unroll 4
    for (int k4 = 0; k4 < 32; ++k4) {
      float4 a4 = *(const float4*)&hT[lane][k4 * 4];
#pragma unroll
      for (int kk = 0; kk < 4; ++kk) {
        float av = (kk == 0) ? a4.x : (kk == 1) ? a4.y : (kk == 2) ? a4.z : a4.w;
        const float* Wrow = &fcwT[(size_t)(k4 * 4 + kk) * 128 + j0];
#pragma unroll
        for (int q = 0; q < 4; ++q) {
          float4 w4 = *(const float4*)&Wrow[4 * q];
          acc[4 * q + 0] += av * w4.x;
          acc[4 * q + 1] += av * w4.y;
          acc[4 * q + 2] += av * w4.z;
          acc[4 * q + 3] += av * w4.w;
        }
      }
    }
    // stage result into aggT (free after phase 1) for coalesced store
#pragma unroll
    for (int q = 0; q < 4; ++q) {
      float4 o4;
      o4.x = acc[4 * q + 0]; o4.y = acc[4 * q + 1];
      o4.z = acc[4 * q + 2]; o4.w = acc[4 * q + 3];
      *(float4*)&aggT[lane][j0 + 4 * q] = o4;
    }
  }
  __syncthreads();

  // coalesced copy-out
  float4* __restrict__ o4p = (float4*)(io + base);
#pragma unroll
  for (int r = 0; r < 4; ++r) {
    int idx = r * 512 + t;
    int rr = idx >> 5;
    if (row0 + rr < N) o4p[idx] = *(const float4*)&aggT[rr][(idx & 31) * 4];
  }
}

extern "C" void kernel_launch(void* const* d_in, const int* in_sizes, int n_in,
                              void* d_out, int out_size, void* d_ws, size_t ws_size,
                              hipStream_t stream) {
  const float* x   = (const float*)d_in[0];
  const int* src   = (const int*)d_in[1];
  const int* dst   = (const int*)d_in[2];
  const float* W   = (const float*)d_in[3];
  const float* b   = (const float*)d_in[4];
  const float* fcW = (const float*)d_in[5];
  const float* fcb = (const float*)d_in[6];
  float* out = (float*)d_out;

  const int N = in_sizes[0] / 128;
  const int E = in_sizes[1];
  const int B = (N + BIN_RANGE - 1) / BIN_RANGE;   // 196 bins (<=256)

  // ws layout (ints), NA = N rounded up to 1024
  const int NA = ((N + 1023) / 1024) * 1024;
  int* wsi = (int*)d_ws;
  int*   deg_out_a   = wsi;                       // [NA]   (zeroed)
  int*   binCnt      = wsi + NA;                  // [256]  (zeroed)
  int*   srcBinCnt   = binCnt + 256;              // [256]  (zeroed)
  int*   binOff      = srcBinCnt + 256;           // [257]
  int*   srcBinOff   = binOff + 257;              // [257]
  int*   binCursor   = srcBinOff + 257;           // [256]
  int*   srcBinCursor= binCursor + 256;           // [256]
  int*   deg_in      = srcBinCursor + 256;        // [NA]
  int*   csr_off     = deg_in + NA;               // [NA]
  float* norm_src    = (float*)(csr_off + NA);    // [NA]
  float* norm_dst    = norm_src + NA;             // [NA]
  float* fcwT        = norm_dst + NA;             // [16384]
  int*   packed      = (int*)(fcwT + 16384);      // [E]  (reused for src pass)
  int*   csr_src     = packed + E;                // [E]
  __half2* xs2       = (__half2*)(csr_src + E);   // [N*64] half2 (25.6MB)

  // 0. zero deg_out + binCnt + srcBinCnt (contiguous NA+512 ints)
  zero_kernel<<<256, 256, 0, stream>>>(wsi, NA + 512);
  // T. fcwT = fcW^T
  transpose128_kernel<<<64, 256, 0, stream>>>(fcW, fcwT);
  // 1-2. coarse histograms + scans (both sides)
  bin_count2_kernel<<<512, 256, 0, stream>>>(src, dst, binCnt, srcBinCnt, E, B);
  bin_scan2_kernel<<<1, 256, 0, stream>>>(binCnt, binOff, binCursor,
                                          srcBinCnt, srcBinOff, srcBinCursor, B);
  // 3-4. dst-side counting sort -> csr_src grouped by dst, csr_off, deg_in
  bin_scatter_kernel<<<(E + 4095) / 4096, 256, 0, stream>>>(src, dst, binCursor, packed, E, B);
  bin_process_kernel<<<B, 256, 0, stream>>>(packed, binOff, csr_src, csr_off, deg_in, N);
  // 5-6. src-side histogram via same machinery (packed buffer reused)
  bin_scatter_src_kernel<<<(E + 4095) / 4096, 256, 0, stream>>>(src, srcBinCursor, packed, E, B);
  bin_process_src_kernel<<<B, 256, 0, stream>>>(packed, srcBinOff, deg_out_a, N);
  // 7. norms
  norm_kernel<<<(N + 255) / 256, 256, 0, stream>>>(deg_out_a, deg_in, norm_src, norm_dst, N);
  // 8. prescale x into fp16
  prescale_kernel<<<2048, 256, 0, stream>>>((const float2*)x, norm_src, xs2, N * 64);
  // 9. aggregate: one wave per node -> d_out holds normalized agg (fp32)
  agg_kernel<<<(N + 3) / 4, 256, 0, stream>>>(xs2, csr_src, csr_off, deg_in,
                                              norm_dst, out, N);
  // 10. fused GEMMs in-place on d_out (64-row tiles)
  gemm_fused_kernel<<<(N + 63) / 64, 512, 0, stream>>>(out, W, b, fcwT, fcb, N);
}